// Round 1
// baseline (427.323 us; speedup 1.0000x reference)
//
#include <hip/hip_runtime.h>
#include <math.h>

#define TPB 256

__global__ __launch_bounds__(TPB) void fused_forward(
    const float* __restrict__ x,        // [N,1,28,28]
    const float* __restrict__ kf_w1,    // [8,1,7,7]
    const float* __restrict__ kf_b1,    // [8]
    const float* __restrict__ kf_w2,    // [10,8,5,5]
    const float* __restrict__ kf_b2,    // [10]
    const float* __restrict__ kf_fc1_w, // [32,90]
    const float* __restrict__ kf_fc1_b, // [32]
    const float* __restrict__ kf_fc2_w, // [40,32]
    const float* __restrict__ kf_fc2_b, // [40]
    const float* __restrict__ conv2_w,  // [20,10,5,5]
    const float* __restrict__ conv2_b,  // [20]
    const float* __restrict__ fc1_w,    // [50,320]
    const float* __restrict__ fc1_b,    // [50]
    const float* __restrict__ fc2_w,    // [10,50]
    const float* __restrict__ fc2_b,    // [10]
    float* __restrict__ out)            // [N,10]
{
    __shared__ float s_x[784];     // input image
    __shared__ float s_w1[392];    // kf_w1
    __shared__ float s_w2[2000];   // kf_w2
    __shared__ float s_w3[5000];   // conv2_w
    __shared__ float s_c1[968];    // pooled relu conv7  [8,11,11]
    __shared__ float s_f[90];      // pooled relu conv5  [10,3,3] flat
    __shared__ float s_h[32];      // kf fc1 out
    __shared__ float s_k[40];      // dynamic kernels [10,2,2]
    __shared__ float s_y[1690];    // pooled relu dyn conv [10,13,13]
    __shared__ float s_c3[1620];   // conv2 raw [20,9,9]
    __shared__ float s_p3[320];    // pooled relu conv2 [20,4,4] flat
    __shared__ float s_a1[50];     // fc1 out
    __shared__ float s_z[10];      // logits

    const int tid = threadIdx.x;
    const int n = blockIdx.x;
    const float* xg = x + (long long)n * 784;

    // ---- stage 0: load image + reused conv weights into LDS ----
    for (int i = tid; i < 784; i += TPB)  s_x[i]  = xg[i];
    for (int i = tid; i < 392; i += TPB)  s_w1[i] = kf_w1[i];
    for (int i = tid; i < 2000; i += TPB) s_w2[i] = kf_w2[i];
    for (int i = tid; i < 5000; i += TPB) s_w3[i] = conv2_w[i];
    __syncthreads();

    // ---- conv7 (28->22) + maxpool2 (->11) + relu, 1->8 ch ----
    // each iteration computes one pooled output = max of 2x2 conv outputs
    for (int idx = tid; idx < 968; idx += TPB) {
        int oc = idx / 121, rem = idx % 121;
        int py = rem / 11, px = rem % 11;
        float a00 = 0.f, a01 = 0.f, a10 = 0.f, a11 = 0.f;
        const float* w = &s_w1[oc * 49];
        #pragma unroll
        for (int ky = 0; ky < 7; ++ky) {
            const float* x0 = &s_x[(2 * py + ky) * 28 + 2 * px];
            const float* x1 = x0 + 28;
            float r0[8], r1[8];
            #pragma unroll
            for (int t = 0; t < 8; ++t) { r0[t] = x0[t]; r1[t] = x1[t]; }
            #pragma unroll
            for (int kx = 0; kx < 7; ++kx) {
                float wv = w[ky * 7 + kx];
                a00 = fmaf(wv, r0[kx],     a00);
                a01 = fmaf(wv, r0[kx + 1], a01);
                a10 = fmaf(wv, r1[kx],     a10);
                a11 = fmaf(wv, r1[kx + 1], a11);
            }
        }
        float m = fmaxf(fmaxf(a00, a01), fmaxf(a10, a11)) + kf_b1[oc];
        s_c1[idx] = fmaxf(m, 0.f);
    }
    __syncthreads();

    // ---- conv5 (11->7) + pool (->3) + relu, 8->10 ch ----
    if (tid < 90) {
        int oc = tid / 9, rem = tid % 9;
        int py = rem / 3, px = rem % 3;
        float a00 = 0.f, a01 = 0.f, a10 = 0.f, a11 = 0.f;
        for (int ic = 0; ic < 8; ++ic) {
            const float* wb = &s_w2[(oc * 8 + ic) * 25];
            #pragma unroll
            for (int ky = 0; ky < 5; ++ky) {
                const float* x0 = &s_c1[ic * 121 + (2 * py + ky) * 11 + 2 * px];
                const float* x1 = x0 + 11;
                float r0[6], r1[6];
                #pragma unroll
                for (int t = 0; t < 6; ++t) { r0[t] = x0[t]; r1[t] = x1[t]; }
                #pragma unroll
                for (int kx = 0; kx < 5; ++kx) {
                    float wv = wb[ky * 5 + kx];
                    a00 = fmaf(wv, r0[kx],     a00);
                    a01 = fmaf(wv, r0[kx + 1], a01);
                    a10 = fmaf(wv, r1[kx],     a10);
                    a11 = fmaf(wv, r1[kx + 1], a11);
                }
            }
        }
        float m = fmaxf(fmaxf(a00, a01), fmaxf(a10, a11)) + kf_b2[oc];
        s_f[tid] = fmaxf(m, 0.f);   // flat [oc*9 + py*3 + px] == tid
    }
    __syncthreads();

    // ---- fc 90->32 + relu ----
    if (tid < 32) {
        float acc = kf_fc1_b[tid];
        const float* wr = &kf_fc1_w[tid * 90];
        for (int i = 0; i < 90; ++i) acc = fmaf(wr[i], s_f[i], acc);
        s_h[tid] = fmaxf(acc, 0.f);
    }
    __syncthreads();

    // ---- fc 32->40 (per-sample dynamic kernels) ----
    if (tid < 40) {
        float acc = kf_fc2_b[tid];
        const float* wr = &kf_fc2_w[tid * 32];
        #pragma unroll
        for (int i = 0; i < 32; ++i) acc = fmaf(wr[i], s_h[i], acc);
        s_k[tid] = acc;   // [oc*4 + di*2 + dj]
    }
    __syncthreads();

    // ---- dynamic 2x2 conv (28->27) + pool (->13) + relu, 10 ch ----
    for (int idx = tid; idx < 1690; idx += TPB) {
        int oc = idx / 169, rem = idx % 169;
        int py = rem / 13, px = rem % 13;
        float k0 = s_k[oc * 4 + 0], k1 = s_k[oc * 4 + 1];
        float k2 = s_k[oc * 4 + 2], k3 = s_k[oc * 4 + 3];
        const float* x0 = &s_x[(2 * py) * 28 + 2 * px];
        float v[3][3];
        #pragma unroll
        for (int r = 0; r < 3; ++r)
            #pragma unroll
            for (int c = 0; c < 3; ++c) v[r][c] = x0[r * 28 + c];
        float c00 = v[0][0]*k0 + v[0][1]*k1 + v[1][0]*k2 + v[1][1]*k3;
        float c01 = v[0][1]*k0 + v[0][2]*k1 + v[1][1]*k2 + v[1][2]*k3;
        float c10 = v[1][0]*k0 + v[1][1]*k1 + v[2][0]*k2 + v[2][1]*k3;
        float c11 = v[1][1]*k0 + v[1][2]*k1 + v[2][1]*k2 + v[2][2]*k3;
        float m = fmaxf(fmaxf(c00, c01), fmaxf(c10, c11));
        s_y[idx] = fmaxf(m, 0.f);
    }
    __syncthreads();

    // ---- conv2 5x5: [10,13,13] -> [20,9,9]; one output row per thread ----
    if (tid < 180) {
        int oc = tid / 9, oy = tid % 9;
        float acc[9];
        float b = conv2_b[oc];
        #pragma unroll
        for (int i = 0; i < 9; ++i) acc[i] = b;
        for (int ic = 0; ic < 10; ++ic) {
            const float* wb = &s_w3[(oc * 10 + ic) * 25];
            #pragma unroll
            for (int ky = 0; ky < 5; ++ky) {
                const float* yr = &s_y[ic * 169 + (oy + ky) * 13];
                float row[13];
                #pragma unroll
                for (int t = 0; t < 13; ++t) row[t] = yr[t];
                #pragma unroll
                for (int kx = 0; kx < 5; ++kx) {
                    float wv = wb[ky * 5 + kx];
                    #pragma unroll
                    for (int ox = 0; ox < 9; ++ox)
                        acc[ox] = fmaf(wv, row[ox + kx], acc[ox]);
                }
            }
        }
        #pragma unroll
        for (int ox = 0; ox < 9; ++ox) s_c3[oc * 81 + oy * 9 + ox] = acc[ox];
    }
    __syncthreads();

    // ---- pool (9->4) + relu -> [20,4,4] flat ----
    for (int idx = tid; idx < 320; idx += TPB) {
        int oc = idx / 16, rem = idx % 16;
        int py = rem / 4, px = rem % 4;
        const float* c = &s_c3[oc * 81 + (2 * py) * 9 + 2 * px];
        float m = fmaxf(fmaxf(c[0], c[1]), fmaxf(c[9], c[10]));
        s_p3[idx] = fmaxf(m, 0.f);
    }
    __syncthreads();

    // ---- fc 320->50 + relu ----
    if (tid < 50) {
        float acc = fc1_b[tid];
        const float* wr = &fc1_w[tid * 320];
        for (int i = 0; i < 320; ++i) acc = fmaf(wr[i], s_p3[i], acc);
        s_a1[tid] = fmaxf(acc, 0.f);
    }
    __syncthreads();

    // ---- fc 50->10 ----
    if (tid < 10) {
        float acc = fc2_b[tid];
        const float* wr = &fc2_w[tid * 50];
        #pragma unroll
        for (int i = 0; i < 50; ++i) acc = fmaf(wr[i], s_a1[i], acc);
        s_z[tid] = acc;
    }
    __syncthreads();

    // ---- log_softmax + store ----
    if (tid < 10) {
        float m = s_z[0];
        #pragma unroll
        for (int i = 1; i < 10; ++i) m = fmaxf(m, s_z[i]);
        float s = 0.f;
        #pragma unroll
        for (int i = 0; i < 10; ++i) s += expf(s_z[i] - m);
        out[n * 10 + tid] = s_z[tid] - m - logf(s);
    }
}

extern "C" void kernel_launch(void* const* d_in, const int* in_sizes, int n_in,
                              void* d_out, int out_size, void* d_ws, size_t ws_size,
                              hipStream_t stream) {
    const float* x        = (const float*)d_in[0];
    const float* kf_w1    = (const float*)d_in[1];
    const float* kf_b1    = (const float*)d_in[2];
    const float* kf_w2    = (const float*)d_in[3];
    const float* kf_b2    = (const float*)d_in[4];
    const float* kf_fc1_w = (const float*)d_in[5];
    const float* kf_fc1_b = (const float*)d_in[6];
    const float* kf_fc2_w = (const float*)d_in[7];
    const float* kf_fc2_b = (const float*)d_in[8];
    const float* conv2_w  = (const float*)d_in[9];
    const float* conv2_b  = (const float*)d_in[10];
    const float* fc1_w    = (const float*)d_in[11];
    const float* fc1_b    = (const float*)d_in[12];
    const float* fc2_w    = (const float*)d_in[13];
    const float* fc2_b    = (const float*)d_in[14];

    const int N = in_sizes[0] / 784;   // 8192

    fused_forward<<<N, TPB, 0, stream>>>(
        x, kf_w1, kf_b1, kf_w2, kf_b2, kf_fc1_w, kf_fc1_b, kf_fc2_w, kf_fc2_b,
        conv2_w, conv2_b, fc1_w, fc1_b, fc2_w, fc2_b, (float*)d_out);
}